// Round 7
// baseline (137.718 us; speedup 1.0000x reference)
//
#include <hip/hip_runtime.h>

typedef unsigned short ushort_t;
typedef unsigned int   uint_t;

typedef __attribute__((ext_vector_type(8))) short  short8;   // 8 bf16 in 4 VGPRs
typedef __attribute__((ext_vector_type(4))) short  short4v;  // 4 bf16 (b64)
typedef __attribute__((ext_vector_type(4))) float  float4v;  // MFMA 16x16 acc

#define BB    8
#define CC    256
#define HH    64
#define WW2   64
#define NPIX  4096   // H*W
#define MPOS  1024   // (H/2)*(W/2)
#define ICH   64

__device__ __forceinline__ float bf2f(ushort_t u) {
  return __uint_as_float(((uint_t)u) << 16);
}
__device__ __forceinline__ ushort_t f2bf(float f) {
  uint_t i = __float_as_uint(f);
  uint_t r = (i + 0x7FFFu + ((i >> 16) & 1u)) >> 16;  // RNE
  return (ushort_t)r;
}
__device__ __forceinline__ ushort_t f2bf_rna(float f) {   // cheap round-half-away
  return (ushort_t)((__float_as_uint(f) + 0x8000u) >> 16);
}
__device__ __forceinline__ uint_t pack2(float a, float b) {
  return (uint_t)f2bf(a) | ((uint_t)f2bf(b) << 16);
}

// ---------------------------------------------------------------------------
// K0: weight prep into coalesced-fragment layouts:
//   wA2 [32 kblk][192 o][8 k]  (A-op frags, 16 consecutive uint4 per quad)
//   Wbf2 [8 icblk][256 o][8 ic] (B-op frags for outconv)
//   biasAll [192] f32
// ---------------------------------------------------------------------------
__global__ __launch_bounds__(256) void prep_kernel(
    const float* __restrict__ theta_w, const float* __restrict__ phi_w,
    const float* __restrict__ g_w, const float* __restrict__ W_w,
    const float* __restrict__ theta_b, const float* __restrict__ phi_b,
    const float* __restrict__ g_b,
    ushort_t* __restrict__ wA2, ushort_t* __restrict__ Wbf2,
    float* __restrict__ biasAll) {
  int i = blockIdx.x * 256 + threadIdx.x;
  if (i < 49152) {         // theta|phi|g -> wA2
    float v = (i < 16384) ? theta_w[i]
            : (i < 32768) ? phi_w[i - 16384]
                          : g_w[i - 32768];
    int o = i >> 8, c = i & 255;
    wA2[(c >> 3) * 1536 + o * 8 + (c & 7)] = f2bf(v);
  } else if (i < 65536) {  // W_w -> Wbf2
    int j = i - 49152;
    int o = j >> 6, ic = j & 63;
    Wbf2[(ic >> 3) * 2048 + o * 8 + (ic & 7)] = f2bf(W_w[j]);
  } else if (i < 65600)    biasAll[i - 65536] = theta_b[i - 65536];
  else if (i < 65664)      biasAll[i - 65536] = phi_b[i - 65600];
  else if (i < 65728)      biasAll[i - 65536] = g_b[i - 65664];
}

// ---------------------------------------------------------------------------
// K1: q/k/v conv GEMM + 2x2 maxpool, reading x fp32 directly.
// Grid 1024 = 8 b x 32 row-pairs x 4 col-quarters; tile = 32 pixels
// (rows {2rj,2rj+1} x cols [16h,16h+16)), K=256 fully resident in LDS (16KB).
// 4 blocks/CU (16 waves/CU). Staging: thread = (pixel, 32-ch group); 32
// coalesced scalar fp32 loads; pack bf16; 4 XOR-swizzled ds_write_b128.
// ONE barrier. Then M=192 x N=32 x K=256 MFMA (48/wave) + pooling epilogue.
// ---------------------------------------------------------------------------
__global__ __launch_bounds__(256, 4) void qkv_kernel(
    const float* __restrict__ x, const ushort_t* __restrict__ wA2,
    const float* __restrict__ biasAll,
    ushort_t* __restrict__ qbuf, ushort_t* __restrict__ kTbuf,
    ushort_t* __restrict__ vTbuf) {
  __shared__ __align__(16) ushort_t Bsu[32 * 256];
  uint4* Bs16 = (uint4*)Bsu;
  int tid = threadIdx.x;
  int wave = tid >> 6, lane = tid & 63;
  int quad = lane >> 4, col = lane & 15;
  int b = blockIdx.x >> 7, t = blockIdx.x & 127;
  int rj = t >> 2, h = t & 3;   // row-pair [0,32), 16-col group [0,4)

  // ---- stage x tile: thread = pixel `pos` (32), channel group `cg` (8x32ch)
  {
    int pos = tid & 31, cg = tid >> 5;
    int prow = pos >> 4, pcol = pos & 15;
    const float* xsrc = x + (size_t)b * (CC * NPIX) +
                        (size_t)(2 * rj + prow) * WW2 + h * 16 + pcol;
    float v[32];
#pragma unroll
    for (int j = 0; j < 32; ++j)
      v[j] = xsrc[(size_t)(cg * 32 + j) * NPIX];
#pragma unroll
    for (int u = 0; u < 4; ++u) {
      uint4 w;
      w.x = pack2(v[u * 8 + 0], v[u * 8 + 1]);
      w.y = pack2(v[u * 8 + 2], v[u * 8 + 3]);
      w.z = pack2(v[u * 8 + 4], v[u * 8 + 5]);
      w.w = pack2(v[u * 8 + 6], v[u * 8 + 7]);
      int jb = cg * 4 + u;  // 16B-block index in K (0..31)
      Bs16[pos * 32 + (jb & ~7) + ((jb & 7) ^ (pos & 7))] = w;
    }
  }
  __syncthreads();

  float4v acc[3][2];
#pragma unroll
  for (int ot = 0; ot < 3; ++ot) {
    int ob = wave * 48 + ot * 16 + quad * 4;
    float4v bv;
#pragma unroll
    for (int r = 0; r < 4; ++r) bv[r] = biasAll[ob + r];
    acc[ot][0] = bv;
    acc[ot][1] = bv;
  }

  const uint4* wA16 = (const uint4*)wA2;
#pragma unroll
  for (int ks = 0; ks < 8; ++ks) {
    int kblk = ks * 4 + quad;               // 16B-block index in K (0..31)
    short8 aw[3];
#pragma unroll
    for (int ot = 0; ot < 3; ++ot) {
      uint4 a = wA16[kblk * 192 + wave * 48 + ot * 16 + col];
      aw[ot] = *(const short8*)&a;
    }
#pragma unroll
    for (int s = 0; s < 2; ++s) {
      int lp = s * 16 + col;
      uint4 braw = Bs16[lp * 32 + (kblk & ~7) + ((kblk & 7) ^ (lp & 7))];
      short8 bx = *(const short8*)&braw;
#pragma unroll
      for (int ot = 0; ot < 3; ++ot)
        acc[ot][s] = __builtin_amdgcn_mfma_f32_16x16x32_bf16(aw[ot], bx, acc[ot][s], 0, 0, 0);
    }
  }

  // epilogue: lane value (o = ob+quad*4+r, local px = s*16+col -> row 2rj+s,
  // global col = h*16+col)
#pragma unroll
  for (int ot = 0; ot < 3; ++ot) {
    int ob = wave * 48 + ot * 16;
    if (ob < 64) {  // theta -> qbuf[b][n][o]
#pragma unroll
      for (int s = 0; s < 2; ++s) {
        int n = (2 * rj + s) * WW2 + h * 16 + col;
        uint2 u;
        u.x = pack2(acc[ot][s][0], acc[ot][s][1]);
        u.y = pack2(acc[ot][s][2], acc[ot][s][3]);
        *(uint2*)&qbuf[((size_t)(b * NPIX + n)) * ICH + ob + quad * 4] = u;
      }
    } else if (ob < 128) {  // phi -> pool -> kTbuf[b][m][ic]
      float4v pm;
#pragma unroll
      for (int r = 0; r < 4; ++r) {
        float v = fmaxf(acc[ot][0][r], acc[ot][1][r]);
        pm[r] = fmaxf(v, __shfl_xor(v, 1));
      }
      if ((lane & 1) == 0) {
        int m = rj * 32 + h * 8 + (col >> 1);
        uint2 u;
        u.x = pack2(pm[0], pm[1]);
        u.y = pack2(pm[2], pm[3]);
        *(uint2*)&kTbuf[((size_t)(b * MPOS + m)) * ICH + (ob - 64) + quad * 4] = u;
      }
    } else {  // g -> pool -> vTbuf[b][ic][m]
      float4v pm;
#pragma unroll
      for (int r = 0; r < 4; ++r) {
        float v = fmaxf(acc[ot][0][r], acc[ot][1][r]);
        pm[r] = fmaxf(v, __shfl_xor(v, 1));
      }
      if ((lane & 1) == 0) {
        int m = rj * 32 + h * 8 + (col >> 1);
#pragma unroll
        for (int r = 0; r < 4; ++r)
          vTbuf[((size_t)(b * ICH + (ob - 128) + quad * 4 + r)) * MPOS + m] = f2bf(pm[r]);
      }
    }
  }
}

// ---------------------------------------------------------------------------
// K2: FUSED attention + output conv + residual (unchanged from r6 — verified).
// ---------------------------------------------------------------------------
__global__ __launch_bounds__(256, 2) void attn_out_kernel(
    const ushort_t* __restrict__ qbuf, const ushort_t* __restrict__ kTbuf,
    const ushort_t* __restrict__ vTbuf, const ushort_t* __restrict__ Wbf2,
    const float* __restrict__ W_b, const float* __restrict__ x,
    float* __restrict__ out) {
  __shared__ __align__(16) ushort_t Ks[2][64 * 64];
  __shared__ __align__(16) ushort_t Vs[2][64 * 64];
  __shared__ __align__(16) ushort_t Ps[64 * 72];
  int tid  = threadIdx.x;
  int wave = tid >> 6, lane = tid & 63;
  int quad = lane >> 4, col = lane & 15;
  int b = blockIdx.x >> 6, qt = blockIdx.x & 63;

  // Q A-fragments straight from global (one-time)
  const ushort_t* qrow = qbuf + ((size_t)(b * NPIX + qt * 64 + wave * 16 + col)) * ICH;
  short8 aQ0 = *(const short8*)&qrow[quad * 8];
  short8 aQ1 = *(const short8*)&qrow[32 + quad * 8];

  int krow0 = tid >> 3,           kblk0 = tid & 7;
  int krow1 = (tid + 256) >> 3,   kblk1 = tid & 7;
  int vic = tid >> 2, vseg = tid & 3;

  const uint4* ksrc0 = (const uint4*)(kTbuf + ((size_t)(b * MPOS)) * ICH);
  const ushort_t* vbase = vTbuf + ((size_t)(b * ICH + vic)) * MPOS;

  {
    uint4 k0 = ksrc0[tid], k1 = ksrc0[tid + 256];
    const uint4* vsrc = (const uint4*)(vbase + vseg * 16);
    uint4 v0 = vsrc[0], v1 = vsrc[1];
    *(uint4*)&Ks[0][krow0 * 64 + ((kblk0 ^ (krow0 & 7)) * 8)] = k0;
    *(uint4*)&Ks[0][krow1 * 64 + ((kblk1 ^ (krow1 & 7)) * 8)] = k1;
    *(uint4*)&Vs[0][vic * 64 + (((vseg * 2 + 0) ^ (vic & 7)) * 8)] = v0;
    *(uint4*)&Vs[0][vic * 64 + (((vseg * 2 + 1) ^ (vic & 7)) * 8)] = v1;
  }
  __syncthreads();

  const float4v zero4 = {0.f, 0.f, 0.f, 0.f};
  float l_lane[4] = {0.f, 0.f, 0.f, 0.f};
  float4v o_acc[4];
#pragma unroll
  for (int t = 0; t < 4; ++t) o_acc[t] = zero4;

  for (int kt = 0; kt < 16; ++kt) {
    uint4 nk0, nk1, nv0, nv1;
    if (kt < 15) {
      const uint4* ksrc = (const uint4*)(kTbuf + ((size_t)(b * MPOS + (kt + 1) * 64)) * ICH);
      nk0 = ksrc[tid];
      nk1 = ksrc[tid + 256];
      const uint4* vsrc = (const uint4*)(vbase + (kt + 1) * 64 + vseg * 16);
      nv0 = vsrc[0];
      nv1 = vsrc[1];
    }
    int buf = kt & 1;

    // S = Q . K^T
    float4v s_acc[4];
#pragma unroll
    for (int t = 0; t < 4; ++t) {
      float4v s = zero4;
      short8 bk0 = *(const short8*)&Ks[buf][(t * 16 + col) * 64 + ((quad ^ (col & 7)) * 8)];
      s = __builtin_amdgcn_mfma_f32_16x16x32_bf16(aQ0, bk0, s, 0, 0, 0);
      short8 bk1 = *(const short8*)&Ks[buf][(t * 16 + col) * 64 + (((4 + quad) ^ (col & 7)) * 8)];
      s = __builtin_amdgcn_mfma_f32_16x16x32_bf16(aQ1, bk1, s, 0, 0, 0);
      s_acc[t] = s;
    }

    // P = exp(S); per-lane l accumulation; wave-private Ps rows
#pragma unroll
    for (int r = 0; r < 4; ++r) {
      int prow = (wave * 16 + quad * 4 + r) * 72;
#pragma unroll
      for (int t = 0; t < 4; ++t) {
        float pv = __expf(s_acc[t][r]);
        l_lane[r] += pv;
        Ps[prow + t * 16 + col] = f2bf_rna(pv);
      }
    }

    // O += P . V
#pragma unroll
    for (int kk = 0; kk < 2; ++kk) {
      short8 ap = *(const short8*)&Ps[(wave * 16 + col) * 72 + kk * 32 + quad * 8];
#pragma unroll
      for (int t = 0; t < 4; ++t) {
        short8 bv = *(const short8*)&Vs[buf][(t * 16 + col) * 64 + (((kk * 4 + quad) ^ (col & 7)) * 8)];
        o_acc[t] = __builtin_amdgcn_mfma_f32_16x16x32_bf16(ap, bv, o_acc[t], 0, 0, 0);
      }
    }

    if (kt < 15) {
      int nbuf = buf ^ 1;
      *(uint4*)&Ks[nbuf][krow0 * 64 + ((kblk0 ^ (krow0 & 7)) * 8)] = nk0;
      *(uint4*)&Ks[nbuf][krow1 * 64 + ((kblk1 ^ (krow1 & 7)) * 8)] = nk1;
      *(uint4*)&Vs[nbuf][vic * 64 + (((vseg * 2 + 0) ^ (vic & 7)) * 8)] = nv0;
      *(uint4*)&Vs[nbuf][vic * 64 + (((vseg * 2 + 1) ^ (vic & 7)) * 8)] = nv1;
      __syncthreads();
    }
  }

  // normalize O, write attended rows (bf16) into wave-private Ps rows.
  // No barrier: each wave only reads back its own rows (same-wave DS order).
#pragma unroll
  for (int r = 0; r < 4; ++r) {
    float l = l_lane[r];
    l += __shfl_xor(l, 1);
    l += __shfl_xor(l, 2);
    l += __shfl_xor(l, 4);
    l += __shfl_xor(l, 8);
    float inv = 1.0f / l;
    int prow = (wave * 16 + quad * 4 + r) * 72;
#pragma unroll
    for (int t = 0; t < 4; ++t)
      Ps[prow + t * 16 + col] = f2bf(o_acc[t][r] * inv);
  }

  // ---- fused output conv: D[m=p(16 per wave)][n=o(256)] + residual ----
  float4v cacc[16];
#pragma unroll
  for (int ot = 0; ot < 16; ++ot) {
    float bv = W_b[ot * 16 + col];
    float4v bvec = {bv, bv, bv, bv};
    cacc[ot] = bvec;
  }
  const uint4* W16 = (const uint4*)Wbf2;
#pragma unroll
  for (int ks = 0; ks < 2; ++ks) {
    short8 ap = *(const short8*)&Ps[(wave * 16 + col) * 72 + ks * 32 + quad * 8];
#pragma unroll
    for (int ot = 0; ot < 16; ++ot) {
      uint4 wr = W16[(ks * 4 + quad) * 256 + ot * 16 + col];
      short8 wf = *(const short8*)&wr;
      cacc[ot] = __builtin_amdgcn_mfma_f32_16x16x32_bf16(ap, wf, cacc[ot], 0, 0, 0);
    }
  }

  int pbase = qt * 64 + wave * 16 + quad * 4;
#pragma unroll
  for (int ot = 0; ot < 16; ++ot) {
    int o = ot * 16 + col;
    size_t idx = ((size_t)(b * CC + o)) * NPIX + pbase;
    float4 xv = *(const float4*)&x[idx];
    float4 ov;
    ov.x = cacc[ot][0] + xv.x;
    ov.y = cacc[ot][1] + xv.y;
    ov.z = cacc[ot][2] + xv.z;
    ov.w = cacc[ot][3] + xv.w;
    *(float4*)&out[idx] = ov;
  }
}

// ---------------------------------------------------------------------------
extern "C" void kernel_launch(void* const* d_in, const int* in_sizes, int n_in,
                              void* d_out, int out_size, void* d_ws, size_t ws_size,
                              hipStream_t stream) {
  const float* x       = (const float*)d_in[0];
  const float* g_w     = (const float*)d_in[1];
  const float* g_b     = (const float*)d_in[2];
  const float* theta_w = (const float*)d_in[3];
  const float* theta_b = (const float*)d_in[4];
  const float* phi_w   = (const float*)d_in[5];
  const float* phi_b   = (const float*)d_in[6];
  const float* W_w     = (const float*)d_in[7];
  const float* W_b     = (const float*)d_in[8];
  (void)in_sizes; (void)n_in; (void)out_size; (void)ws_size;

  char* ws = (char*)d_ws;
  ushort_t* wA2     = (ushort_t*)(ws + 0);         // 96KB bf16 [32][192][8]
  ushort_t* Wbf2    = (ushort_t*)(ws + 98304);     // 32KB bf16 [8][256][8]
  float*    biasAll = (float*)(ws + 131072);       // 768B
  ushort_t* qbuf    = (ushort_t*)(ws + 262144);    // 4MB bf16 [8][4096][64]
  ushort_t* kTbuf   = (ushort_t*)(ws + 4456448);   // 1MB bf16 [8][1024][64]
  ushort_t* vTbuf   = (ushort_t*)(ws + 5505024);   // 1MB bf16 [8][64][1024]
  float* out = (float*)d_out;

  prep_kernel<<<257, 256, 0, stream>>>(theta_w, phi_w, g_w, W_w,
                                       theta_b, phi_b, g_b,
                                       wA2, Wbf2, biasAll);
  qkv_kernel<<<1024, 256, 0, stream>>>(x, wA2, biasAll, qbuf, kTbuf, vTbuf);
  attn_out_kernel<<<512, 256, 0, stream>>>(qbuf, kTbuf, vTbuf, Wbf2, W_b, x, out);
}